// Round 7
// baseline (232.298 us; speedup 1.0000x reference)
//
#include <hip/hip_runtime.h>

#define NA 4096
#define NB 4096
#define DIM 256
#define DK 64
#define PSTR 72            // pbuf row stride (bf16 elements)
#define WSTR 68            // wm LDS row stride (f32 elements)
#define NSPLIT 8           // b-range splits (grid.y)
#define BIT (NB / NSPLIT / 64)   // 8 K-iterations per block

typedef __attribute__((ext_vector_type(8))) short bf16x8;
typedef __attribute__((ext_vector_type(4))) float f32x4;
typedef __attribute__((ext_vector_type(4))) unsigned short us4;
typedef __attribute__((ext_vector_type(4))) int i32x4;
typedef __attribute__((ext_vector_type(2))) unsigned int u32x2;

static __device__ __forceinline__ float bf2f(unsigned short u) {
    union { unsigned int u; float f; } x;
    x.u = ((unsigned int)u) << 16;
    return x.f;
}
static __device__ __forceinline__ unsigned short f2bf(float f) {
    union { float f; unsigned int u; } x;
    x.f = f;
    unsigned int r = x.u + 0x7fffu + ((x.u >> 16) & 1u);
    return (unsigned short)(r >> 16);
}

// ---------------------------------------------------------------------------
// Fragment-major layouts (lane-contiguous: element for lane l at base+l*8):
//  XF/WF (proj inputs): flat = ((tile*8 + ki)*64 + l)*8 + e
//      holds  X[tile*16 + (l&15)][ki*32 + (l>>4)*8 + e]
//  QF/KF (attn QK):     flat = (((head*256 + t16)*2 + ks)*64 + l)*8 + e
//      holds  M[t16*16 + (l&15)][head*64 + ks*32 + (l>>4)*8 + e]
//  VF (attn PV):        flat = ((((head*64 + t64)*4 + nt)*2 + ks2)*64 + l)*8 + e
//      holds  V^T[head*64 + nt*16 + (l&15)][t64*64 + ks2*32 + (l>>4)*8 + e]
// ---------------------------------------------------------------------------

// ---------------------------------------------------------------------------
// prep: fp32 -> (bf16 hi, lo) split of a_z, bv_z, Wq/Wk/Wv, frag-major out.
// ---------------------------------------------------------------------------
__global__ __launch_bounds__(256) void prep_kernel(
    const float* __restrict__ a_z, const float* __restrict__ bv,
    const float* __restrict__ Wq, const float* __restrict__ Wk,
    const float* __restrict__ Wv,
    unsigned short* __restrict__ ah, unsigned short* __restrict__ al,
    unsigned short* __restrict__ bh, unsigned short* __restrict__ bl,
    unsigned short* __restrict__ wh, unsigned short* __restrict__ wl)
{
    const int idx = blockIdx.x * 256 + threadIdx.x;
    const int y = blockIdx.y;
    const float* __restrict__ src;
    unsigned short* __restrict__ dh;
    unsigned short* __restrict__ dl;
    int row, col;
    if (y == 0) {
        src = a_z; dh = ah; dl = al;
        row = (idx >> 9) * 16 + (idx & 15);
        col = ((idx >> 6) & 7) * 32 + ((idx >> 4) & 3) * 8;
    } else if (y == 1) {
        src = bv; dh = bh; dl = bl;
        row = (idx >> 9) * 16 + (idx & 15);
        col = ((idx >> 6) & 7) * 32 + ((idx >> 4) & 3) * 8;
    } else {
        if (idx >= 3 * 8192) return;
        const int m = idx >> 13;
        const int im = idx & 8191;
        src = (m == 0) ? Wq : ((m == 1) ? Wk : Wv);
        dh = wh; dl = wl;
        row = (im >> 9) * 16 + (im & 15);
        col = ((im >> 6) & 7) * 32 + ((im >> 4) & 3) * 8;
    }
    f32x4 v0 = *(const f32x4*)(src + row * DIM + col);
    f32x4 v1 = *(const f32x4*)(src + row * DIM + col + 4);
    bf16x8 h8, l8;
    #pragma unroll
    for (int r = 0; r < 4; ++r) {
        unsigned short h0 = f2bf(v0[r]);
        h8[r] = (short)h0;  l8[r] = (short)f2bf(v0[r] - bf2f(h0));
        unsigned short h1 = f2bf(v1[r]);
        h8[4 + r] = (short)h1;  l8[4 + r] = (short)f2bf(v1[r] - bf2f(h1));
    }
    *(bf16x8*)(dh + idx * 8) = h8;
    *(bf16x8*)(dl + idx * 8) = l8;
}

// ---------------------------------------------------------------------------
// proj: pure bf16 MFMA GEMM, frag-major in AND out (unchanged from r5).
// ---------------------------------------------------------------------------
__global__ __launch_bounds__(256, 2) void proj_kernel(
    const unsigned short* __restrict__ ah, const unsigned short* __restrict__ al,
    const unsigned short* __restrict__ bh, const unsigned short* __restrict__ bl,
    const unsigned short* __restrict__ whc, const unsigned short* __restrict__ wlc,
    unsigned short* __restrict__ qhi, unsigned short* __restrict__ qlo,
    unsigned short* __restrict__ khi, unsigned short* __restrict__ vtout)
{
    const int mat = blockIdx.z;
    const unsigned short* __restrict__ Xh = (mat == 0) ? ah : bh;
    const unsigned short* __restrict__ Xl = (mat == 0) ? al : bl;
    const unsigned short* __restrict__ Wh = whc + mat * 65536;
    const unsigned short* __restrict__ Wl = wlc + mat * 65536;

    const int tid  = threadIdx.x;
    const int wv   = tid >> 6;
    const int lane = tid & 63;
    const int c    = lane & 15;
    const int quad = lane >> 4;
    const int n0 = blockIdx.x * 64;
    const int by = blockIdx.y;

    const unsigned short* xhp = Xh + (n0 >> 4) * 4096 + lane * 8;
    const unsigned short* xlp = Xl + (n0 >> 4) * 4096 + lane * 8;
    const unsigned short* whp = Wh + (by * 4 + wv) * 4096 + lane * 8;
    const unsigned short* wlp = Wl + (by * 4 + wv) * 4096 + lane * 8;

    f32x4 acc[4];
    #pragma unroll
    for (int nt = 0; nt < 4; ++nt) acc[nt] = (f32x4){0.f, 0.f, 0.f, 0.f};

    bf16x8 wAh, wAl, xAh[4], xAl[4];
    bf16x8 wBh, wBl, xBh[4], xBl[4];

    wAh = *(const bf16x8*)(whp);
    wAl = *(const bf16x8*)(wlp);
    #pragma unroll
    for (int nt = 0; nt < 4; ++nt) {
        xAh[nt] = *(const bf16x8*)(xhp + nt * 4096);
        xAl[nt] = *(const bf16x8*)(xlp + nt * 4096);
    }

    #pragma unroll
    for (int kk = 0; kk < 8; kk += 2) {
        wBh = *(const bf16x8*)(whp + (kk + 1) * 512);
        wBl = *(const bf16x8*)(wlp + (kk + 1) * 512);
        #pragma unroll
        for (int nt = 0; nt < 4; ++nt) {
            xBh[nt] = *(const bf16x8*)(xhp + nt * 4096 + (kk + 1) * 512);
            xBl[nt] = *(const bf16x8*)(xlp + nt * 4096 + (kk + 1) * 512);
        }
        #pragma unroll
        for (int nt = 0; nt < 4; ++nt) {
            acc[nt] = __builtin_amdgcn_mfma_f32_16x16x32_bf16(xAh[nt], wAh, acc[nt], 0, 0, 0);
            acc[nt] = __builtin_amdgcn_mfma_f32_16x16x32_bf16(xAl[nt], wAh, acc[nt], 0, 0, 0);
            acc[nt] = __builtin_amdgcn_mfma_f32_16x16x32_bf16(xAh[nt], wAl, acc[nt], 0, 0, 0);
        }
        if (kk + 2 < 8) {
            wAh = *(const bf16x8*)(whp + (kk + 2) * 512);
            wAl = *(const bf16x8*)(wlp + (kk + 2) * 512);
            #pragma unroll
            for (int nt = 0; nt < 4; ++nt) {
                xAh[nt] = *(const bf16x8*)(xhp + nt * 4096 + (kk + 2) * 512);
                xAl[nt] = *(const bf16x8*)(xlp + nt * 4096 + (kk + 2) * 512);
            }
        }
        #pragma unroll
        for (int nt = 0; nt < 4; ++nt) {
            acc[nt] = __builtin_amdgcn_mfma_f32_16x16x32_bf16(xBh[nt], wBh, acc[nt], 0, 0, 0);
            acc[nt] = __builtin_amdgcn_mfma_f32_16x16x32_bf16(xBl[nt], wBh, acc[nt], 0, 0, 0);
            acc[nt] = __builtin_amdgcn_mfma_f32_16x16x32_bf16(xBh[nt], wBl, acc[nt], 0, 0, 0);
        }
    }

    if (mat != 2) {
        const int ks = wv >> 1;
        const int lq = ((wv & 1) * 2 + (c >> 3)) * 16 + quad * 4;
        const int e  = c & 7;
        #pragma unroll
        for (int nt = 0; nt < 4; ++nt) {
            const int tbase = (((by * 256 + (n0 >> 4) + nt) * 2 + ks) * 64 + lq) * 8 + e;
            #pragma unroll
            for (int r = 0; r < 4; ++r) {
                const int idx = tbase + r * 8;
                if (mat == 0) {
                    unsigned short h = f2bf(acc[nt][r]);
                    qhi[idx] = h;
                    qlo[idx] = f2bf(acc[nt][r] - bf2f(h));
                } else {
                    khi[idx] = f2bf(acc[nt][r]);
                }
            }
        }
    } else {
        #pragma unroll
        for (int nt = 0; nt < 4; ++nt) {
            const int lv = ((nt & 1) * 2 + (quad >> 1)) * 16 + c;
            const int idx = ((((by * 64 + (n0 >> 6)) * 4 + wv) * 2 + (nt >> 1)) * 64 + lv) * 8
                            + (quad & 1) * 4;
            us4 p;
            #pragma unroll
            for (int r = 0; r < 4; ++r) p[r] = f2bf(acc[nt][r]);
            *(us4*)(vtout + idx) = p;
        }
    }
}

// ---------------------------------------------------------------------------
// attn v5: K register double-buffer with drain-correct issue order.
//  Per iter: [V(t)] [wm(t+1)] || QK on K(t) || [K(t+1)] || softmax/PV/wm-write.
//  Wait analysis (vmcnt counts outstanding, youngest-first):
//    QK needs K(t):  newer = V(8)+wm(2)  -> waits leaving 10 in flight
//    PV needs V(t):  newer = wm(2)+K(8)  -> waits leaving 10 in flight
//    wm-write needs wm: newer = K(8)     -> waits leaving 8 in flight
//    next QK needs K(t+1): issued ~600cy earlier -> fully hidden
//  (r2's dbuf failed because V was issued last -> every PV drained all.)
//  P pack via v_cvt_pk_bf16_f32 (HW RNE, bit-identical to manual f2bf,
//  -40 VALU/iter). den via ones-column MFMA. Frag-major K/V/Q loads.
// ---------------------------------------------------------------------------
__global__ __launch_bounds__(256, 2) void attn_kernel(
    const unsigned short* __restrict__ qhg,
    const unsigned short* __restrict__ qlg,
    const unsigned short* __restrict__ kg,
    const unsigned short* __restrict__ vtg,
    const float* __restrict__ wg,
    const int* __restrict__ mg,
    float* __restrict__ pnum,
    float* __restrict__ pden)
{
    __shared__ float wmbuf[2][16 * WSTR];
    __shared__ unsigned short pbuf[4][16 * PSTR];

    const int tid  = threadIdx.x;
    const int wv   = tid >> 6;      // head
    const int lane = tid & 63;
    const int c    = lane & 15;
    const int quad = lane >> 4;

    // bijective XCD swizzle: XCD x gets b-split x, all 256 a-tiles
    const int flat = blockIdx.y * 256 + blockIdx.x;
    const int swz  = (flat & 7) * 256 + (flat >> 3);
    const int a0   = (swz & 255) * 16;
    const int bs   = swz >> 8;
    const int bbase = bs * (NB / NSPLIT);

    const int sa = tid >> 4;
    const int sb = (tid & 15) * 4;

    unsigned kbase = (unsigned)((wv * 256 + (bbase >> 4)) * 1024 + lane * 8);
    unsigned vbase = (unsigned)((wv * 64 + (bbase >> 6)) * 4096 + lane * 8);
    const unsigned qbase = (unsigned)((wv * 256 + (a0 >> 4)) * 1024 + lane * 8);

    bf16x8 qh[2], ql[2];
    qh[0] = *(const bf16x8*)(qhg + qbase);
    qh[1] = *(const bf16x8*)(qhg + qbase + 512);
    ql[0] = *(const bf16x8*)(qlg + qbase);
    ql[1] = *(const bf16x8*)(qlg + qbase + 512);

    bf16x8 ones;
    #pragma unroll
    for (int r = 0; r < 8; ++r) ones[r] = (short)0x3F80;

    f32x4 num[4];
    #pragma unroll
    for (int nt = 0; nt < 4; ++nt) num[nt] = (f32x4){0.f, 0.f, 0.f, 0.f};
    f32x4 dacc = (f32x4){0.f, 0.f, 0.f, 0.f};

    unsigned woff = (unsigned)((a0 + sa) * NB + bbase + sb);

    // prologue: stage wm tile 0, issue K(0)
    {
        f32x4 w = *(const f32x4*)(wg + woff);
        i32x4 m = *(const i32x4*)(mg + woff);
        f32x4 wm;
        #pragma unroll
        for (int r = 0; r < 4; ++r) wm[r] = m[r] ? w[r] : -1.0e9f;
        *(f32x4*)(&wmbuf[0][sa * WSTR + sb]) = wm;
    }
    woff += 64;

    bf16x8 kA[4][2], kB[4][2];
    #pragma unroll
    for (int bt = 0; bt < 4; ++bt)
        #pragma unroll
        for (int ks = 0; ks < 2; ++ks)
            kA[bt][ks] = *(const bf16x8*)(kg + kbase + bt * 1024 + ks * 512);
    kbase += 4096;

#define ITER(IT, KCUR, KNXT)                                                   \
    {                                                                          \
        const int cur = (IT) & 1;                                              \
        const bool more = ((IT) + 1 < BIT);                                    \
        __syncthreads();  /* wmbuf[cur] ready; wmbuf[cur^1] free */            \
        /* --- V(t) loads (consumed at PV) --- */                              \
        bf16x8 vf[4][2];                                                       \
        _Pragma("unroll")                                                      \
        for (int nt = 0; nt < 4; ++nt)                                         \
            _Pragma("unroll")                                                  \
            for (int ks2 = 0; ks2 < 2; ++ks2)                                  \
                vf[nt][ks2] = *(const bf16x8*)(vtg + vbase + nt * 1024 + ks2 * 512); \
        /* --- wm(t+1) loads (consumed at end of iter) --- */                  \
        f32x4 wnxt; i32x4 mnxt;                                                \
        if (more) {                                                            \
            wnxt = *(const f32x4*)(wg + woff);                                 \
            mnxt = *(const i32x4*)(mg + woff);                                 \
        }                                                                      \
        __builtin_amdgcn_sched_barrier(0);                                     \
        /* --- QK on KCUR (waits leave V+wm in flight) --- */                  \
        f32x4 S[4];                                                            \
        __builtin_amdgcn_s_setprio(1);                                         \
        _Pragma("unroll")                                                      \
        for (int bt = 0; bt < 4; ++bt) {                                       \
            f32x4 s = (f32x4){0.f, 0.f, 0.f, 0.f};                             \
            s = __builtin_amdgcn_mfma_f32_16x16x32_bf16(KCUR[bt][0], qh[0], s, 0, 0, 0); \
            s = __builtin_amdgcn_mfma_f32_16x16x32_bf16(KCUR[bt][1], qh[1], s, 0, 0, 0); \
            s = __builtin_amdgcn_mfma_f32_16x16x32_bf16(KCUR[bt][0], ql[0], s, 0, 0, 0); \
            s = __builtin_amdgcn_mfma_f32_16x16x32_bf16(KCUR[bt][1], ql[1], s, 0, 0, 0); \
            S[bt] = s;                                                         \
        }                                                                      \
        __builtin_amdgcn_s_setprio(0);                                         \
        /* --- K(t+1) loads (consumed next iter; ~600cy slack) --- */          \
        if (more) {                                                            \
            _Pragma("unroll")                                                  \
            for (int bt = 0; bt < 4; ++bt)                                     \
                _Pragma("unroll")                                              \
                for (int ks = 0; ks < 2; ++ks)                                 \
                    KNXT[bt][ks] = *(const bf16x8*)(kg + kbase + bt * 1024 + ks * 512); \
        }                                                                      \
        __builtin_amdgcn_sched_barrier(0);                                     \
        kbase += 4096; vbase += 4096; woff += 64;                              \
        /* --- wm fragments from LDS --- */                                    \
        f32x4 wf[4];                                                           \
        _Pragma("unroll")                                                      \
        for (int bt = 0; bt < 4; ++bt)                                         \
            wf[bt] = *(const f32x4*)(&wmbuf[cur][c * WSTR + bt * 16 + quad * 4]); \
        /* --- softmax + cvt_pk pack: lane holds (a=c, b=bt*16+quad*4+r) --- */\
        _Pragma("unroll")                                                      \
        for (int bt = 0; bt < 4; ++bt) {                                       \
            float ev[4];                                                       \
            _Pragma("unroll")                                                  \
            for (int r = 0; r < 4; ++r) {                                      \
                float t = fmaf(S[bt][r], 0.125f, wf[bt][r]);                   \
                t = __builtin_amdgcn_fmed3f(t, -10.0f, 10.0f);                 \
                ev[r] = exp2f(t * 1.4426950408889634f);                        \
            }                                                                  \
            unsigned p0, p1;                                                   \
            asm("v_cvt_pk_bf16_f32 %0, %1, %2" : "=v"(p0) : "v"(ev[0]), "v"(ev[1])); \
            asm("v_cvt_pk_bf16_f32 %0, %1, %2" : "=v"(p1) : "v"(ev[2]), "v"(ev[3])); \
            u32x2 pp; pp[0] = p0; pp[1] = p1;                                  \
            *(u32x2*)(&pbuf[wv][c * PSTR + bt * 16 + quad * 4]) = pp;          \
        }                                                                      \
        /* --- PV + den (waits leave wm+K in flight) --- */                    \
        bf16x8 pf[2];                                                          \
        _Pragma("unroll")                                                      \
        for (int ks2 = 0; ks2 < 2; ++ks2)                                      \
            pf[ks2] = *(const bf16x8*)(&pbuf[wv][c * PSTR + ks2 * 32 + quad * 8]); \
        __builtin_amdgcn_s_setprio(1);                                         \
        _Pragma("unroll")                                                      \
        for (int nt = 0; nt < 4; ++nt) {                                       \
            num[nt] = __builtin_amdgcn_mfma_f32_16x16x32_bf16(pf[0], vf[nt][0], num[nt], 0, 0, 0); \
            num[nt] = __builtin_amdgcn_mfma_f32_16x16x32_bf16(pf[1], vf[nt][1], num[nt], 0, 0, 0); \
        }                                                                      \
        dacc = __builtin_amdgcn_mfma_f32_16x16x32_bf16(pf[0], ones, dacc, 0, 0, 0); \
        dacc = __builtin_amdgcn_mfma_f32_16x16x32_bf16(pf[1], ones, dacc, 0, 0, 0); \
        __builtin_amdgcn_s_setprio(0);                                         \
        /* --- wm(t+1) fold + LDS write (waits leave K in flight) --- */       \
        if (more) {                                                            \
            f32x4 wm;                                                          \
            _Pragma("unroll")                                                  \
            for (int r = 0; r < 4; ++r) wm[r] = mnxt[r] ? wnxt[r] : -1.0e9f;   \
            *(f32x4*)(&wmbuf[cur ^ 1][sa * WSTR + sb]) = wm;                   \
        }                                                                      \
    }

    #pragma unroll
    for (int ito = 0; ito < BIT; ito += 2) {
        ITER(ito,     kA, kB)
        ITER(ito + 1, kB, kA)
    }
#undef ITER

    // den: dacc C-layout row = quad*4+r = a-offset, every col holds a copy
    const int hb = (bs * 4 + wv) * NA + a0;
    if (c == 0) {
        #pragma unroll
        for (int r = 0; r < 4; ++r)
            pden[hb + quad * 4 + r] = dacc[r];
    }

    // num C-layout: col = lane&15 = dk-sub, row = quad*4+r = a
    #pragma unroll
    for (int nt = 0; nt < 4; ++nt)
        #pragma unroll
        for (int r = 0; r < 4; ++r)
            pnum[(size_t)(hb + quad * 4 + r) * DK + nt * 16 + c] = num[nt][r];
}

// ---------------------------------------------------------------------------
// reduce: combine b-split partials, divide, average heads; influence = 1.0
// ---------------------------------------------------------------------------
__global__ __launch_bounds__(256) void reduce_kernel(
    const float* __restrict__ pnum, const float* __restrict__ pden,
    float* __restrict__ outp)
{
    const int idx = blockIdx.x * 256 + threadIdx.x;   // over NA*DK
    const int a = idx >> 6, dd = idx & 63;
    float s = 0.0f;
    #pragma unroll
    for (int h = 0; h < 4; ++h) {
        float n = 0.0f, d = 0.0f;
        #pragma unroll
        for (int b = 0; b < NSPLIT; ++b) {
            n += pnum[(size_t)((b * 4 + h) * NA + a) * DK + dd];
            d += pden[(b * 4 + h) * NA + a];
        }
        s += n / d;
    }
    outp[idx] = 0.25f * s;
    if (dd == 0) outp[NA * DK + a] = 1.0f;   // softmax rows sum to 1
}

extern "C" void kernel_launch(void* const* d_in, const int* in_sizes, int n_in,
                              void* d_out, int out_size, void* d_ws, size_t ws_size,
                              hipStream_t stream) {
    const float* a_z = (const float*)d_in[0];
    const float* bv  = (const float*)d_in[1];
    const int* mask  = (const int*)d_in[2];
    const float* wgt = (const float*)d_in[3];
    const float* Wq  = (const float*)d_in[4];
    const float* Wk  = (const float*)d_in[5];
    const float* Wv  = (const float*)d_in[6];
    float* out = (float*)d_out;

    // persistent attn inputs
    unsigned short* qhi = (unsigned short*)d_ws;       // QF hi [4][256][2][64][8]
    unsigned short* qlo = qhi + NA * DIM;              // QF lo
    unsigned short* khi = qlo + NA * DIM;              // KF
    unsigned short* vt  = khi + NB * DIM;              // VF
    float* pnum = (float*)(vt + (size_t)DIM * NB);     // [NSPLIT][4][NA][DK]
    float* pden = pnum + (size_t)NSPLIT * 4 * NA * DK; // [NSPLIT][4][NA]
    // prep/proj scratch overlapped INSIDE pnum (proj finishes before attn
    // writes pnum; stream-ordered => safe). Span 9.2 MB < pnum 33.5 MB.
    unsigned short* ah  = (unsigned short*)pnum;       // XF a hi
    unsigned short* al  = ah + NA * DIM;
    unsigned short* bh  = al + NA * DIM;
    unsigned short* bl  = bh + NB * DIM;
    unsigned short* whc = bl + NB * DIM;               // WF [3][16][8][64][8]
    unsigned short* wlc = whc + 3 * 65536;

    prep_kernel<<<dim3(512, 3), 256, 0, stream>>>(a_z, bv, Wq, Wk, Wv,
                                                  ah, al, bh, bl, whc, wlc);
    proj_kernel<<<dim3(64, 4, 3), 256, 0, stream>>>(ah, al, bh, bl, whc, wlc,
                                                    qhi, qlo, khi, vt);
    attn_kernel<<<dim3(256, NSPLIT), 256, 0, stream>>>(qhi, qlo, khi, vt,
                                                       wgt, mask, pnum, pden);
    reduce_kernel<<<dim3(NA * DK / 256), 256, 0, stream>>>(pnum, pden, out);
}